// Round 14
// baseline (156.824 us; speedup 1.0000x reference)
//
#include <hip/hip_runtime.h>
#include <hip/hip_fp16.h>

#define Nn 2048
#define Ff 64
#define Uu 64
#define NT 512
#define NCH 4           // chunks of 512 cols
#define G1S 68

typedef _Float16 f16x4 __attribute__((ext_vector_type(4)));
typedef _Float16 f16x8 __attribute__((ext_vector_type(8)));
typedef float    f32x4 __attribute__((ext_vector_type(4)));

#define MFMA32(a,b,c) __builtin_amdgcn_mfma_f32_16x16x32_f16(a,b,c,0,0,0)

// LDS: P dbuf [c&1]{batch0 16KB, batch1 16KB} = 64KB; g1 aliased in buf0
#define OWS   65536    // 32 floats
#define OINV  65664    // 32 floats
#define SMSZ  65792

// ---- X transpose: Xt[b][f][k] = (f16) X[b][k][f] (validated R4-R13) ----
__global__ __launch_bounds__(256) void transposeX(const float* __restrict__ X,
                                                  _Float16* __restrict__ Xt) {
    __shared__ _Float16 tile[64][65];
    const int b = blockIdx.x, kt = blockIdx.y;
    #pragma unroll
    for (int i = 0; i < 16; ++i) {
        int e  = i * 256 + threadIdx.x;
        int kk = e >> 6, ff = e & 63;
        tile[ff][kk] = (_Float16)X[((size_t)b * Nn + kt * 64 + kk) * Ff + ff];
    }
    __syncthreads();
    #pragma unroll
    for (int i = 0; i < 16; ++i) {
        int e  = i * 256 + threadIdx.x;
        int ff = e >> 6, kk = e & 63;
        Xt[((size_t)b * Ff + ff) * Nn + kt * 64 + kk] = tile[ff][kk];
    }
}

// Unit = 1 row x 256 cols, BOTH batches; Geo/KL loaded once (shared).
// Every load = 64 lanes x 16B = 1KB contiguous (R6-proven).
#define ISSUE2(d0v,d1v,gv,kv,w00,w01,w02,w10,w11,w12, C, UR, H) {   \
    const size_t _o = (size_t)(UR) * Nn + ((size_t)(C) << 9)        \
                    + ((H) << 8) + (lane << 2);                     \
    d0v = *(const float4*)(dR0 + _o);                               \
    d1v = *(const float4*)(dR1 + _o);                               \
    gv  = *(const float4*)(gR + _o);                                \
    kv  = *(const float4*)(kR + _o);                                \
    w00 = *(const float4*)(wR0 + 3 * _o);                           \
    w01 = *(const float4*)(wR0 + 3 * _o + 4);                       \
    w02 = *(const float4*)(wR0 + 3 * _o + 8);                       \
    w10 = *(const float4*)(wR1 + 3 * _o);                           \
    w11 = *(const float4*)(wR1 + 3 * _o + 4);                       \
    w12 = *(const float4*)(wR1 + 3 * _o + 8);                       \
}

// exp for both batches -> swizzled f16 P tiles + register row-sums.
#define CONSUME2(d0v,d1v,gv,kv,w00,w01,w02,w10,w11,w12, P0B,P1B, UR, H) {       \
    const int _tr = row0 + (UR);                                                \
    float a0 = __expf(fminf(d0v.x*w00.x + gv.x*w00.y + kv.x*w00.z, 11.f));      \
    float a1 = __expf(fminf(d0v.y*w00.w + gv.y*w01.x + kv.y*w01.y, 11.f));      \
    float a2 = __expf(fminf(d0v.z*w01.z + gv.z*w01.w + kv.z*w02.x, 11.f));      \
    float a3 = __expf(fminf(d0v.w*w02.y + gv.w*w02.z + kv.w*w02.w, 11.f));      \
    float c0 = __expf(fminf(d1v.x*w10.x + gv.x*w10.y + kv.x*w10.z, 11.f));      \
    float c1 = __expf(fminf(d1v.y*w10.w + gv.y*w11.x + kv.y*w11.y, 11.f));      \
    float c2 = __expf(fminf(d1v.z*w11.z + gv.z*w11.w + kv.z*w12.x, 11.f));      \
    float c3 = __expf(fminf(d1v.w*w12.y + gv.w*w12.z + kv.w*w12.w, 11.f));      \
    f16x4 h0 = {(_Float16)a0, (_Float16)a1, (_Float16)a2, (_Float16)a3};        \
    f16x4 h1 = {(_Float16)c0, (_Float16)c1, (_Float16)c2, (_Float16)c3};        \
    rs0[UR] += (float)h0[0] + (float)h0[1] + (float)h0[2] + (float)h0[3];       \
    rs1[UR] += (float)h1[0] + (float)h1[1] + (float)h1[2] + (float)h1[3];       \
    const int _ba = (_tr * 1024 + ((H) << 9) + (lane << 3))                     \
                    ^ ((_tr & 7) << 4);                                         \
    *(f16x4*)((P0B) + _ba) = h0;                                                \
    *(f16x4*)((P1B) + _ba) = h1;                                                \
}

// depth-2 stage of one 512-col chunk: 4 units = 2 rows x 2 halves
#define STAGE_CHUNK2(P0B, P1B, C) {                                              \
    ISSUE2(Ad0,Ad1,Agv,Akv,Aw00,Aw01,Aw02,Aw10,Aw11,Aw12, C, 0, 0);              \
    ISSUE2(Bd0,Bd1,Bgv,Bkv,Bw00,Bw01,Bw02,Bw10,Bw11,Bw12, C, 0, 1);              \
    CONSUME2(Ad0,Ad1,Agv,Akv,Aw00,Aw01,Aw02,Aw10,Aw11,Aw12, P0B,P1B, 0, 0);      \
    ISSUE2(Ad0,Ad1,Agv,Akv,Aw00,Aw01,Aw02,Aw10,Aw11,Aw12, C, 1, 0);              \
    CONSUME2(Bd0,Bd1,Bgv,Bkv,Bw00,Bw01,Bw02,Bw10,Bw11,Bw12, P0B,P1B, 0, 1);      \
    ISSUE2(Bd0,Bd1,Bgv,Bkv,Bw00,Bw01,Bw02,Bw10,Bw11,Bw12, C, 1, 1);              \
    CONSUME2(Ad0,Ad1,Agv,Akv,Aw00,Aw01,Aw02,Aw10,Aw11,Aw12, P0B,P1B, 1, 0);      \
    CONSUME2(Bd0,Bd1,Bgv,Bkv,Bw00,Bw01,Bw02,Bw10,Bw11,Bw12, P0B,P1B, 1, 1);      \
}

// MFMA over one staged 512-col chunk (R8-verified 2-group prefetch form).
#define MFMA_PHASE2(PBUF, XC) {                                               \
    f16x8 p0 = *(const f16x8*)((XC));                                         \
    f16x8 p1 = *(const f16x8*)((XC) + 32);                                    \
    f16x8 p2 = *(const f16x8*)((XC) + 64);                                    \
    f16x8 p3 = *(const f16x8*)((XC) + 96);                                    \
    f16x8 p4 = *(const f16x8*)((XC) + 128);                                   \
    f16x8 p5 = *(const f16x8*)((XC) + 160);                                   \
    f16x8 p6 = *(const f16x8*)((XC) + 192);                                   \
    f16x8 p7 = *(const f16x8*)((XC) + 224);                                   \
    _Pragma("unroll")                                                         \
    for (int kk = 0; kk < 8; ++kk) {                                          \
        const int aa = r * 1024 + kk * 64 + kg * 16;                          \
        f16x8 af = *(const f16x8*)((PBUF) + (aa ^ ((r & 7) << 4)));           \
        f16x8 bv = (kk==0)?p0:(kk==1)?p1:(kk==2)?p2:(kk==3)?p3:               \
                   (kk==4)?p4:(kk==5)?p5:(kk==6)?p6:p7;                       \
        acc = MFMA32(af, bv, acc);                                            \
    }                                                                         \
    p0 = *(const f16x8*)((XC) + 256);                                         \
    p1 = *(const f16x8*)((XC) + 288);                                         \
    p2 = *(const f16x8*)((XC) + 320);                                         \
    p3 = *(const f16x8*)((XC) + 352);                                         \
    p4 = *(const f16x8*)((XC) + 384);                                         \
    p5 = *(const f16x8*)((XC) + 416);                                         \
    p6 = *(const f16x8*)((XC) + 448);                                         \
    p7 = *(const f16x8*)((XC) + 480);                                         \
    _Pragma("unroll")                                                         \
    for (int kk = 0; kk < 8; ++kk) {                                          \
        const int aa = r * 1024 + (kk + 8) * 64 + kg * 16;                    \
        f16x8 af = *(const f16x8*)((PBUF) + (aa ^ ((r & 7) << 4)));           \
        f16x8 bv = (kk==0)?p0:(kk==1)?p1:(kk==2)?p2:(kk==3)?p3:               \
                   (kk==4)?p4:(kk==5)?p5:(kk==6)?p6:p7;                       \
        acc = MFMA32(af, bv, acc);                                            \
    }                                                                         \
}

// 512-thread block = 16 rows x 2 batches. 8 waves: each stages 2 rows
// (Geo/KL once for both batches) and computes ONE MFMA tile (batch wid>>2,
// col-tile wid&3). Grid 512 x 2 blocks/CU = 16 streaming waves/CU — the
// R6-verified rate — at the NB=2 byte count (677 MB vs 790).
__global__ __launch_bounds__(NT, 4) void fused_gcn(
    const _Float16* __restrict__ Xt,  // [B,F,N] f16
    const float* __restrict__ Dyn,    // [B,N,N]
    const float* __restrict__ Wf,     // [B,N,N,3]
    const float* __restrict__ Geo,    // [N,N]
    const float* __restrict__ KLm,    // [N,N]
    const float* __restrict__ Wd,     // [F,U]
    const float* __restrict__ bdv,    // [U]
    float* __restrict__ out)          // [B,N,U]
{
    __shared__ __align__(16) char SM[SMSZ];

    const int t    = threadIdx.x;
    const int lane = t & 63;
    const int wid  = t >> 6;           // 0..7
    const int r    = lane & 15;
    const int kg   = lane >> 4;
    const int rg   = blockIdx.x & 127;
    const int pp   = blockIdx.x >> 7;
    const int n0   = rg << 4;
    const int b0   = pp * 2, b1 = pp * 2 + 1;
    const int row0 = wid << 1;         // staging rows row0, row0+1

    const float* dR0 = Dyn + ((size_t)b0 * Nn + n0 + row0) * Nn;
    const float* dR1 = Dyn + ((size_t)b1 * Nn + n0 + row0) * Nn;
    const float* wR0 = Wf  + ((size_t)b0 * Nn + n0 + row0) * (size_t)Nn * 3;
    const float* wR1 = Wf  + ((size_t)b1 * Nn + n0 + row0) * (size_t)Nn * 3;
    const float* gR  = Geo + (size_t)(n0 + row0) * Nn;
    const float* kR  = KLm + (size_t)(n0 + row0) * Nn;

    // MFMA role: batch bb = wid>>2, col-tile ct = wid&3
    const int bb = wid >> 2, ct = wid & 3;
    const _Float16* xwv = Xt + (size_t)(bb ? b1 : b0) * Ff * Nn
                        + (size_t)(ct * 16 + r) * Nn + (kg << 3);

    f32x4 acc = {0.f,0.f,0.f,0.f};
    float rs0[2] = {0.f,0.f}, rs1[2] = {0.f,0.f};
    float4 Ad0,Ad1,Agv,Akv,Aw00,Aw01,Aw02,Aw10,Aw11,Aw12;
    float4 Bd0,Bd1,Bgv,Bkv,Bw00,Bw01,Bw02,Bw10,Bw11,Bw12;

    // prologue: stage chunk 0
    STAGE_CHUNK2(SM, SM + 16384, 0);
    __syncthreads();

    #pragma unroll 1
    for (int c = 0; c < NCH; ++c) {
        const char* pb = SM + (c & 1) * 32768 + bb * 16384;
        MFMA_PHASE2(pb, xwv + ((size_t)c << 9));
        if (c + 1 < NCH) {
            char* bufn = SM + ((c + 1) & 1) * 32768;
            STAGE_CHUNK2(bufn, bufn + 16384, c + 1);
        }
        __syncthreads();
    }

    // ---- row sums -> inv (batch0 rows 0-15, batch1 rows 16-31) ----
    float* ws = (float*)(SM + OWS);
    #pragma unroll
    for (int i = 0; i < 2; ++i) {
        float v = rs0[i];
        v += __shfl_xor(v, 1, 64);  v += __shfl_xor(v, 2, 64);
        v += __shfl_xor(v, 4, 64);  v += __shfl_xor(v, 8, 64);
        v += __shfl_xor(v, 16, 64); v += __shfl_xor(v, 32, 64);
        float u = rs1[i];
        u += __shfl_xor(u, 1, 64);  u += __shfl_xor(u, 2, 64);
        u += __shfl_xor(u, 4, 64);  u += __shfl_xor(u, 8, 64);
        u += __shfl_xor(u, 16, 64); u += __shfl_xor(u, 32, 64);
        if (lane == 0) { ws[row0 + i] = v; ws[16 + row0 + i] = u; }
    }
    __syncthreads();
    float* inv = (float*)(SM + OINV);
    if (t < 32) inv[t] = 1.0f / ws[t];
    __syncthreads();

    // ---- normalized G1 tiles, aliased into P buffer 0 (all reads done) ----
    float* g1a = (float*)SM;
    float* g1b = (float*)(SM + 4352);
    float* g1w = bb ? g1b : g1a;
    #pragma unroll
    for (int i = 0; i < 4; ++i) {
        const int ro = (kg << 2) + i;
        g1w[ro * G1S + ct * 16 + r] = acc[i] * inv[bb * 16 + ro];
    }
    __syncthreads();

    // ---- Dense(64) + tanh: wave -> batch wid>>2, rows (wid&3)*4..+3 ----
    const int rw0 = (wid & 3) << 2;
    const float* gg = (bb ? g1b : g1a) + rw0 * G1S;
    const int ob = bb ? b1 : b0;
    float bias = bdv[lane];
    float o0 = bias, o1 = bias, o2 = bias, o3 = bias;
    #pragma unroll 4
    for (int f = 0; f < Ff; ++f) {
        float wdv = Wd[f * Uu + lane];
        o0 += gg[f] * wdv;           o1 += gg[G1S + f] * wdv;
        o2 += gg[2 * G1S + f] * wdv; o3 += gg[3 * G1S + f] * wdv;
    }
    float oo[4] = {o0, o1, o2, o3};
    #pragma unroll
    for (int i = 0; i < 4; ++i) {
        float x  = fminf(fmaxf(oo[i], -15.f), 15.f);
        float ex = __expf(2.f * x);
        out[((size_t)ob * Nn + n0 + rw0 + i) * Uu + lane] = (ex - 1.f) / (ex + 1.f);
    }
}

extern "C" void kernel_launch(void* const* d_in, const int* in_sizes, int n_in,
                              void* d_out, int out_size, void* d_ws, size_t ws_size,
                              hipStream_t stream) {
    const float* X   = (const float*)d_in[0];
    const float* Dyn = (const float*)d_in[1];
    const float* Wf  = (const float*)d_in[2];
    const float* Geo = (const float*)d_in[3];
    const float* KLm = (const float*)d_in[4];
    const float* Wd  = (const float*)d_in[5];
    const float* bdv = (const float*)d_in[6];
    float* out = (float*)d_out;

    _Float16* Xt = (_Float16*)d_ws;   // 2 MB scratch
    transposeX<<<dim3(8, Nn / 64), dim3(256), 0, stream>>>(X, Xt);
    fused_gcn<<<dim3(4 * 128), dim3(NT), 0, stream>>>(
        Xt, Dyn, Wf, Geo, KLm, Wd, bdv, out);
}